// Round 2
// baseline (2789.799 us; speedup 1.0000x reference)
//
#include <hip/hip_runtime.h>
#include <hip/hip_bf16.h>
#include <math.h>

#define Bx   256
#define Nx   512
#define SIGx 256
#define HIDx 256
#define OUTx 10
#define Hx   256

// ---- storage-type helpers (t1/t2 may be fp32 or bf16 depending on ws_size) --
__device__ inline void storeT(float* p, float v)          { *p = v; }
__device__ inline void storeT(__hip_bfloat16* p, float v) { *p = __float2bfloat16(v); }
__device__ inline float loadT(const float* p)             { return *p; }
__device__ inline float loadT(const __hip_bfloat16* p)    { return __bfloat162float(*p); }

// ---------------------------------------------------------------------------
// Kernel A: per-(b,n) sampling stage. Mixture fields are constant in m
// (value raw[n/32, j]) => unif/idx are dead. Computes logprob sum (output 1),
// loc, pixel gather, feat = [pv, locx, locy].
// ---------------------------------------------------------------------------
__global__ __launch_bounds__(512) void kA_sample(
    const float* __restrict__ x, const float* __restrict__ z,
    const float* __restrict__ mg, float* __restrict__ feat,
    float* __restrict__ flp)
{
    int b = blockIdx.x;
    int n = threadIdx.x;            // 512
    int g = n >> 5;                 // n / 32
    float mux = mg[g*6+1];
    float muy = mg[g*6+2];
    float sxv = expf(mg[g*6+3]);
    float syv = expf(mg[g*6+4]);
    float rho = tanhf(mg[g*6+5]);
    float z1 = z[((size_t)b*Nx + n)*2 + 0];
    float z2 = z[((size_t)b*Nx + n)*2 + 1];
    float omr2 = 1.0f - rho*rho;
    float xs = mux + sxv*z1;
    float ys = muy + syv*(rho*z1 + sqrtf(omr2)*z2);
    float dx = xs - mux;
    float dy = ys - muy;
    float quad = (dx*dx/(sxv*sxv) - 2.0f*rho*dx*dy/(sxv*syv) + dy*dy/(syv*syv)) / omr2;
    float logprob = -1.8378770664093453f - logf(sxv*syv) - 0.5f*logf(omr2) - 0.5f*quad;
    float lx = tanhf(xs), ly = tanhf(ys);
    int px = (int)truncf(0.5f*(lx+1.0f)*(float)Hx - 0.1f);
    int py = (int)truncf(0.5f*(ly+1.0f)*(float)Hx - 0.1f);
    px = px < 0 ? 0 : (px > Hx-1 ? Hx-1 : px);
    py = py < 0 ? 0 : (py > Hx-1 ? Hx-1 : py);
    float pv = x[(size_t)b*Hx*Hx + (size_t)px*Hx + py];
    size_t fo = ((size_t)b*Nx + n)*3;
    feat[fo+0] = pv; feat[fo+1] = lx; feat[fo+2] = ly;

    __shared__ float red[512];
    red[n] = logprob;
    __syncthreads();
    for (int st = 256; st > 0; st >>= 1) {
        if (n < st) red[n] += red[n+st];
        __syncthreads();
    }
    if (n == 0) flp[b] = red[0];
}

// ---------------------------------------------------------------------------
// Kernel B: h1[bn,h] = feat[bn,0:3] . gc1_w[0:3,h]   (NFEAT=3) — chunked
// ---------------------------------------------------------------------------
__global__ __launch_bounds__(256) void kB_h1(
    const float* __restrict__ featL, const float* __restrict__ w1,
    float* __restrict__ h1)
{
    int idx = blockIdx.x*256 + threadIdx.x;   // BC*N*HID total
    int h  = idx & (HIDx-1);
    int bn = idx >> 8;
    const float* f = featL + (size_t)bn*3;
    h1[idx] = f[0]*w1[h] + f[1]*w1[HIDx+h] + f[2]*w1[2*HIDx+h];
}

// ---------------------------------------------------------------------------
// Kernel C: sout[b,n,h] = relu( sum_m adj(b;n,m) * hin[b,m,h] + bias[h] )
// adj recomputed on the fly from loc. b is chunk-local. Block: 8 n-rows.
// ---------------------------------------------------------------------------
__global__ __launch_bounds__(256) void kC_adjmm(
    const float* __restrict__ featL, const float* __restrict__ hin,
    const float* __restrict__ bias, float* __restrict__ sout)
{
    int b   = blockIdx.y;           // chunk-local batch
    int n0  = blockIdx.x * 8;
    int tid = threadIdx.x;
    __shared__ float lx_s[Nx], ly_s[Nx];
    __shared__ float adj_s[8][Nx];
    const float* fb = featL + (size_t)b*Nx*3;
    for (int m = tid; m < Nx; m += 256) {
        lx_s[m] = fb[m*3+1];
        ly_s[m] = fb[m*3+2];
    }
    __syncthreads();
    for (int idx = tid; idx < 8*Nx; idx += 256) {
        int r = idx >> 9;
        int m = idx & (Nx-1);
        float dx = lx_s[n0+r] - lx_s[m];
        float dy = ly_s[n0+r] - ly_s[m];
        adj_s[r][m] = 1.0f/(1.0f + 0.5f*(dx*dx + dy*dy));
    }
    __syncthreads();
    float acc[8] = {0,0,0,0,0,0,0,0};
    const float* hb = hin + (size_t)b*Nx*HIDx + tid;
    for (int m = 0; m < Nx; m += 4) {
        float hv0 = hb[(size_t)(m+0)*HIDx];
        float hv1 = hb[(size_t)(m+1)*HIDx];
        float hv2 = hb[(size_t)(m+2)*HIDx];
        float hv3 = hb[(size_t)(m+3)*HIDx];
        #pragma unroll
        for (int r = 0; r < 8; ++r) {
            float4 av = *(const float4*)&adj_s[r][m];
            acc[r] = fmaf(av.x, hv0, acc[r]);
            acc[r] = fmaf(av.y, hv1, acc[r]);
            acc[r] = fmaf(av.z, hv2, acc[r]);
            acc[r] = fmaf(av.w, hv3, acc[r]);
        }
    }
    float bv = bias[tid];
    #pragma unroll
    for (int r = 0; r < 8; ++r)
        sout[((size_t)b*Nx + n0 + r)*HIDx + tid] = fmaxf(acc[r] + bv, 0.0f);
}

// ---------------------------------------------------------------------------
// Kernel D: t[b,s,h] = sum_n c[s,n] * sin_[b,n,h]  (b chunk-local; t offset by
// caller). Output type T in {float, bf16}.
// ---------------------------------------------------------------------------
template<typename T>
__global__ __launch_bounds__(256) void kD_collapse(
    const float* __restrict__ c, const float* __restrict__ sin_,
    T* __restrict__ t)
{
    int b   = blockIdx.y;
    int s0  = blockIdx.x * 8;
    int tid = threadIdx.x;
    __shared__ float c_s[8*Nx];
    for (int idx = tid; idx < 8*Nx; idx += 256) c_s[idx] = c[(size_t)s0*Nx + idx];
    __syncthreads();
    float acc[8] = {0,0,0,0,0,0,0,0};
    const float* sb = sin_ + (size_t)b*Nx*HIDx + tid;
    for (int n = 0; n < Nx; n += 4) {
        float sv0 = sb[(size_t)(n+0)*HIDx];
        float sv1 = sb[(size_t)(n+1)*HIDx];
        float sv2 = sb[(size_t)(n+2)*HIDx];
        float sv3 = sb[(size_t)(n+3)*HIDx];
        #pragma unroll
        for (int r = 0; r < 8; ++r) {
            float4 cv = *(const float4*)&c_s[r*Nx + n];
            acc[r] = fmaf(cv.x, sv0, acc[r]);
            acc[r] = fmaf(cv.y, sv1, acc[r]);
            acc[r] = fmaf(cv.z, sv2, acc[r]);
            acc[r] = fmaf(cv.w, sv3, acc[r]);
        }
    }
    #pragma unroll
    for (int r = 0; r < 8; ++r)
        storeT(&t[((size_t)b*SIGx + s0 + r)*HIDx + tid], acc[r]);
}

// ---------------------------------------------------------------------------
// Kernel E: hout[row,h] = sum_k sin_[row,k] * w[k,h]   (rows = BC*N)
// ---------------------------------------------------------------------------
__global__ __launch_bounds__(256) void kE_dense(
    const float* __restrict__ sin_, const float* __restrict__ w,
    float* __restrict__ hout)
{
    size_t row0 = (size_t)blockIdx.x * 8;
    int tid = threadIdx.x;
    __shared__ float s_s[8*HIDx];
    for (int idx = tid; idx < 8*HIDx; idx += 256) s_s[idx] = sin_[row0*HIDx + idx];
    __syncthreads();
    float acc[8] = {0,0,0,0,0,0,0,0};
    for (int k = 0; k < HIDx; k += 4) {
        float wv0 = w[(k+0)*HIDx + tid];
        float wv1 = w[(k+1)*HIDx + tid];
        float wv2 = w[(k+2)*HIDx + tid];
        float wv3 = w[(k+3)*HIDx + tid];
        #pragma unroll
        for (int r = 0; r < 8; ++r) {
            float4 sv = *(const float4*)&s_s[r*HIDx + k];
            acc[r] = fmaf(sv.x, wv0, acc[r]);
            acc[r] = fmaf(sv.y, wv1, acc[r]);
            acc[r] = fmaf(sv.z, wv2, acc[r]);
            acc[r] = fmaf(sv.w, wv3, acc[r]);
        }
    }
    #pragma unroll
    for (int r = 0; r < 8; ++r) hout[(row0 + r)*HIDx + tid] = acc[r];
}

// ---------------------------------------------------------------------------
// Kernel F1: softmax-over-b stats for t1, t2 (layout [b][s][h]).
// ---------------------------------------------------------------------------
template<typename T>
__global__ __launch_bounds__(256) void kF1_stats(
    const T* __restrict__ t1, const T* __restrict__ t2,
    float* __restrict__ m1, float* __restrict__ d1,
    float* __restrict__ m2, float* __restrict__ d2)
{
    int s = blockIdx.x;
    int h = threadIdx.x;
    size_t base = (size_t)s*HIDx + h;
    const size_t str = (size_t)SIGx*HIDx;
    float mx = -3.0e38f;
    for (int b = 0; b < Bx; ++b) mx = fmaxf(mx, loadT(&t1[(size_t)b*str + base]));
    float dd = 0.0f;
    for (int b = 0; b < Bx; ++b) dd += expf(loadT(&t1[(size_t)b*str + base]) - mx);
    m1[base] = mx; d1[base] = dd;
    mx = -3.0e38f;
    for (int b = 0; b < Bx; ++b) mx = fmaxf(mx, loadT(&t2[(size_t)b*str + base]));
    dd = 0.0f;
    for (int b = 0; b < Bx; ++b) dd += expf(loadT(&t2[(size_t)b*str + base]) - mx);
    m2[base] = mx; d2[base] = dd;
}

// ---------------------------------------------------------------------------
// Kernel F2: sig[b,s] = sum_h g1[b,s,h] + g2[b,s,h]
// ---------------------------------------------------------------------------
template<typename T>
__global__ __launch_bounds__(256) void kF2_sig(
    const T* __restrict__ t1, const T* __restrict__ t2,
    const float* __restrict__ m1, const float* __restrict__ d1,
    const float* __restrict__ m2, const float* __restrict__ d2,
    float* __restrict__ sig)
{
    int s = blockIdx.x;
    int b = blockIdx.y;
    int h = threadIdx.x;
    size_t sh = (size_t)s*HIDx + h;
    size_t tb = ((size_t)b*SIGx + s)*HIDx + h;
    float v = expf(loadT(&t1[tb]) - m1[sh]) / d1[sh]
            + expf(loadT(&t2[tb]) - m2[sh]) / d2[sh];
    __shared__ float red[256];
    red[h] = v;
    __syncthreads();
    for (int st = 128; st > 0; st >>= 1) {
        if (h < st) red[h] += red[h+st];
        __syncthreads();
    }
    if (h == 0) sig[(size_t)b*SIGx + s] = red[0];
}

// ---------------------------------------------------------------------------
// Kernel G: out[b,:] = softmax(sig[b,:] @ fcf_w.T + fcf_b)
// ---------------------------------------------------------------------------
__global__ __launch_bounds__(256) void kG_out(
    const float* __restrict__ sig, const float* __restrict__ fw,
    const float* __restrict__ fb, float* __restrict__ out)
{
    int b = blockIdx.x;
    int tid = threadIdx.x;
    __shared__ float red[256];
    __shared__ float logits[OUTx];
    float sv = sig[(size_t)b*SIGx + tid];
    for (int o = 0; o < OUTx; ++o) {
        red[tid] = sv * fw[o*SIGx + tid];
        __syncthreads();
        for (int st = 128; st > 0; st >>= 1) {
            if (tid < st) red[tid] += red[tid+st];
            __syncthreads();
        }
        if (tid == 0) logits[o] = red[0] + fb[o];
        __syncthreads();
    }
    if (tid == 0) {
        float mx = logits[0];
        for (int o = 1; o < OUTx; ++o) mx = fmaxf(mx, logits[o]);
        float dd = 0.0f; float e[OUTx];
        for (int o = 0; o < OUTx; ++o) { e[o] = expf(logits[o]-mx); dd += e[o]; }
        float inv = 1.0f/dd;
        for (int o = 0; o < OUTx; ++o) out[(size_t)b*OUTx + o] = e[o]*inv;
    }
}

// ---------------------------------------------------------------------------
static inline size_t alignup(size_t b) { return (b + 255) & ~(size_t)255; }

template<typename T>
static void run_pipeline(const float* x, const float* z, const float* mg,
                         const float* w1, const float* b1,
                         const float* w2, const float* b2,
                         const float* c1, const float* c2,
                         const float* fw, const float* fbv,
                         float* out, float* flp,
                         char* ws, int BC, hipStream_t stream)
{
    size_t off = 0;
    auto alloc = [&](size_t bytes) -> char* {
        char* p = ws + off; off += alignup(bytes); return p;
    };
    float* feat  = (float*)alloc((size_t)Bx*Nx*3*4);
    float* ebuf0 = (float*)alloc((size_t)BC*Nx*HIDx*4);   // h1_c / h2_c
    float* ebuf1 = (float*)alloc((size_t)BC*Nx*HIDx*4);   // s1_c / s2_c
    T*     t1    = (T*)alloc((size_t)Bx*SIGx*HIDx*sizeof(T));
    T*     t2    = (T*)alloc((size_t)Bx*SIGx*HIDx*sizeof(T));
    float* m1    = (float*)alloc((size_t)SIGx*HIDx*4);
    float* d1    = (float*)alloc((size_t)SIGx*HIDx*4);
    float* m2    = (float*)alloc((size_t)SIGx*HIDx*4);
    float* d2    = (float*)alloc((size_t)SIGx*HIDx*4);
    float* sig   = (float*)alloc((size_t)Bx*SIGx*4);

    hipLaunchKernelGGL(kA_sample, dim3(Bx), dim3(Nx), 0, stream, x, z, mg, feat, flp);

    const int nch = Bx / BC;
    for (int c = 0; c < nch; ++c) {
        int b0 = c * BC;
        const float* featL = feat + (size_t)b0*Nx*3;
        T* t1L = t1 + (size_t)b0*SIGx*HIDx;
        T* t2L = t2 + (size_t)b0*SIGx*HIDx;
        // h1_c = feat @ gc1_w
        hipLaunchKernelGGL(kB_h1, dim3(BC*Nx), dim3(256), 0, stream, featL, w1, ebuf0);
        // s1_c = relu(adj @ h1 + b1)
        hipLaunchKernelGGL(kC_adjmm, dim3(Nx/8, BC), dim3(256), 0, stream, featL, ebuf0, b1, ebuf1);
        // t1_c = c1 @ s1
        hipLaunchKernelGGL(kD_collapse<T>, dim3(SIGx/8, BC), dim3(256), 0, stream, c1, ebuf1, t1L);
        // h2_c = s1 @ gc2_w
        hipLaunchKernelGGL(kE_dense, dim3((BC*Nx)/8), dim3(256), 0, stream, ebuf1, w2, ebuf0);
        // s2_c = relu(adj @ h2 + b2)   (s1 dead -> overwrite ebuf1)
        hipLaunchKernelGGL(kC_adjmm, dim3(Nx/8, BC), dim3(256), 0, stream, featL, ebuf0, b2, ebuf1);
        // t2_c = c2 @ s2
        hipLaunchKernelGGL(kD_collapse<T>, dim3(SIGx/8, BC), dim3(256), 0, stream, c2, ebuf1, t2L);
    }

    hipLaunchKernelGGL(kF1_stats<T>, dim3(SIGx), dim3(256), 0, stream, t1, t2, m1, d1, m2, d2);
    hipLaunchKernelGGL(kF2_sig<T>, dim3(SIGx, Bx), dim3(256), 0, stream, t1, t2, m1, d1, m2, d2, sig);
    hipLaunchKernelGGL(kG_out, dim3(Bx), dim3(256), 0, stream, sig, fw, fbv, out);
}

extern "C" void kernel_launch(void* const* d_in, const int* in_sizes, int n_in,
                              void* d_out, int out_size, void* d_ws, size_t ws_size,
                              hipStream_t stream)
{
    const float* x   = (const float*)d_in[0];
    // d_in[1] = unif — dead (mixture fields constant over m)
    const float* z   = (const float*)d_in[2];
    const float* mg  = (const float*)d_in[3];
    const float* w1  = (const float*)d_in[4];
    const float* b1  = (const float*)d_in[5];
    const float* w2  = (const float*)d_in[6];
    const float* b2  = (const float*)d_in[7];
    const float* c1  = (const float*)d_in[8];
    const float* c2  = (const float*)d_in[9];
    const float* fw  = (const float*)d_in[10];
    const float* fbv = (const float*)d_in[11];
    float* out = (float*)d_out;               // (B, OUT) flat
    float* flp = out + (size_t)Bx*OUTx;       // (B,)
    (void)in_sizes; (void)n_in; (void)out_size;

    // ---- adaptive workspace plan (depends only on ws_size -> graph-safe) ----
    const size_t featB  = alignup((size_t)Bx*Nx*3*4);
    const size_t statsB = 4*alignup((size_t)SIGx*HIDx*4) + alignup((size_t)Bx*SIGx*4);
    const size_t tF     = alignup((size_t)Bx*SIGx*HIDx*4);           // fp32 t
    const size_t tH     = alignup((size_t)Bx*SIGx*HIDx*2);           // bf16 t

    int BC = 0; bool use_bf16 = false;
    for (int c = Bx; c >= 1; c >>= 1) {
        size_t need = featB + statsB + 2*tF + 2*alignup((size_t)c*Nx*HIDx*4);
        if (need <= ws_size) { BC = c; break; }
    }
    if (BC == 0) {
        use_bf16 = true;
        for (int c = Bx; c >= 1; c >>= 1) {
            size_t need = featB + statsB + 2*tH + 2*alignup((size_t)c*Nx*HIDx*4);
            if (need <= ws_size) { BC = c; break; }
        }
        if (BC == 0) BC = 1;  // last resort
    }

    if (!use_bf16)
        run_pipeline<float>(x, z, mg, w1, b1, w2, b2, c1, c2, fw, fbv,
                            out, flp, (char*)d_ws, BC, stream);
    else
        run_pipeline<__hip_bfloat16>(x, z, mg, w1, b1, w2, b2, c1, c2, fw, fbv,
                                     out, flp, (char*)d_ws, BC, stream);
}

// Round 4
// 534.344 us; speedup vs baseline: 5.2210x; 5.2210x over previous
//
#include <hip/hip_runtime.h>
#include <hip/hip_bf16.h>
#include <math.h>

#define Bx   256
#define Nx   512
#define SIGx 256
#define HIDx 256
#define OUTx 10
#define Hx   256

#define LDAP 72   // LDS k-stride (bf16 elems): 144 B rows, 16B-aligned, banks spread

typedef __attribute__((ext_vector_type(8))) short bf16x8;
typedef __attribute__((ext_vector_type(4))) float f32x4;

__device__ inline ushort f2bf(float v) {
    __hip_bfloat16 h = __float2bfloat16(v);
    return *reinterpret_cast<ushort*>(&h);
}
__device__ inline float loadT(const __hip_bfloat16* p) { return __bfloat162float(*p); }

// ---------------------------------------------------------------------------
// Kernel A: sampling stage (mixture fields constant over m => unif dead).
// Outputs: flp (output 1), feat[b][n][{pv,lx,ly}] fp32.
// ---------------------------------------------------------------------------
__global__ __launch_bounds__(512) void kA_sample(
    const float* __restrict__ x, const float* __restrict__ z,
    const float* __restrict__ mg, float* __restrict__ feat,
    float* __restrict__ flp)
{
    int b = blockIdx.x;
    int n = threadIdx.x;
    int g = n >> 5;
    float mux = mg[g*6+1];
    float muy = mg[g*6+2];
    float sxv = expf(mg[g*6+3]);
    float syv = expf(mg[g*6+4]);
    float rho = tanhf(mg[g*6+5]);
    float z1 = z[((size_t)b*Nx + n)*2 + 0];
    float z2 = z[((size_t)b*Nx + n)*2 + 1];
    float omr2 = 1.0f - rho*rho;
    float xs = mux + sxv*z1;
    float ys = muy + syv*(rho*z1 + sqrtf(omr2)*z2);
    float dx = xs - mux, dy = ys - muy;
    float quad = (dx*dx/(sxv*sxv) - 2.0f*rho*dx*dy/(sxv*syv) + dy*dy/(syv*syv)) / omr2;
    float logprob = -1.8378770664093453f - logf(sxv*syv) - 0.5f*logf(omr2) - 0.5f*quad;
    float lx = tanhf(xs), ly = tanhf(ys);
    int px = (int)truncf(0.5f*(lx+1.0f)*(float)Hx - 0.1f);
    int py = (int)truncf(0.5f*(ly+1.0f)*(float)Hx - 0.1f);
    px = px < 0 ? 0 : (px > Hx-1 ? Hx-1 : px);
    py = py < 0 ? 0 : (py > Hx-1 ? Hx-1 : py);
    float pv = x[(size_t)b*Hx*Hx + (size_t)px*Hx + py];
    size_t fo = ((size_t)b*Nx + n)*3;
    feat[fo+0] = pv; feat[fo+1] = lx; feat[fo+2] = ly;

    __shared__ float red[512];
    red[n] = logprob;
    __syncthreads();
    for (int st = 256; st > 0; st >>= 1) {
        if (n < st) red[n] += red[n+st];
        __syncthreads();
    }
    if (n == 0) flp[b] = red[0];
}

// ---------------------------------------------------------------------------
// Prep: c1,c2 -> bf16 (same layout), w2 -> w2t bf16 (transposed). One-time.
// ---------------------------------------------------------------------------
__global__ __launch_bounds__(256) void kPrep(
    const float* __restrict__ c1, const float* __restrict__ c2,
    const float* __restrict__ w2,
    ushort* __restrict__ c1h, ushort* __restrict__ c2h, ushort* __restrict__ w2t)
{
    int idx = blockIdx.x*256 + threadIdx.x;   // grid 512 -> 131072
    if (idx < SIGx*Nx) {
        c1h[idx] = f2bf(c1[idx]);
        c2h[idx] = f2bf(c2[idx]);
    }
    if (idx < HIDx*HIDx) {
        int i = idx >> 8, j = idx & 255;      // w2t[i][j] = w2[j][i]
        w2t[idx] = f2bf(w2[j*HIDx + i]);
    }
}

// ---------------------------------------------------------------------------
// kB: h1t[b][h][n] = bf16( pv[n]*w1[0][h] + lx[n]*w1[1][h] + ly[n]*w1[2][h] )
// grid (4 h-slabs, BC), 256 thr; packed b32 stores coalesced over n.
// ---------------------------------------------------------------------------
__global__ __launch_bounds__(256) void kB_h1t(
    const float* __restrict__ featL, const float* __restrict__ w1,
    ushort* __restrict__ h1tAll)
{
    int b = blockIdx.y;
    int hs = blockIdx.x * 64;
    const float* fb = featL + (size_t)b*Nx*3;
    ushort* h1t = h1tAll + (size_t)b*HIDx*Nx;
    __shared__ float fpv[Nx], flx[Nx], fly[Nx];
    int t = threadIdx.x;
    for (int n = t; n < Nx; n += 256) {
        fpv[n] = fb[n*3+0]; flx[n] = fb[n*3+1]; fly[n] = fb[n*3+2];
    }
    __syncthreads();
    int n0 = 2*t;
    float p0 = fpv[n0],   x0 = flx[n0],   y0 = fly[n0];
    float p1 = fpv[n0+1], x1 = flx[n0+1], y1 = fly[n0+1];
    for (int hh = 0; hh < 64; ++hh) {
        int h = hs + hh;
        float w0 = w1[h], wA = w1[HIDx+h], wB = w1[2*HIDx+h];
        float v0 = fmaf(p0,w0, fmaf(x0,wA, y0*wB));
        float v1 = fmaf(p1,w0, fmaf(x1,wA, y1*wB));
        uint pk = (uint)f2bf(v0) | ((uint)f2bf(v1) << 16);
        *(uint*)(h1t + (size_t)h*Nx + n0) = pk;
    }
}

// ---------------------------------------------------------------------------
// kGadj: C[h][n] = sum_m A[h][m] * adj[m][n]  (adj symmetric, gen'd on the fly)
// A = h-transposed activation [256][512] bf16; epilogue bias[h]+relu -> sT.
// grid (8 = 2 rowtiles x 4 coltiles, BC), 256 thr (4 waves, 64x64 each).
// ---------------------------------------------------------------------------
__global__ __launch_bounds__(256) void kGadj(
    const ushort* __restrict__ Aall, const float* __restrict__ featL,
    const float* __restrict__ bias, ushort* __restrict__ outAll)
{
    int b  = blockIdx.y;
    int rt = blockIdx.x >> 2;
    int ct = blockIdx.x & 3;
    const ushort* A = Aall + (size_t)b*HIDx*Nx;
    ushort* outT = outAll + (size_t)b*HIDx*Nx;
    const float* fb = featL + (size_t)b*Nx*3;

    __shared__ short Als[128][LDAP];
    __shared__ short Bls[128][LDAP];
    __shared__ float lxs[Nx], lys[Nx];

    int t = threadIdx.x;
    for (int n = t; n < Nx; n += 256) {
        lxs[n] = fb[n*3+1];
        lys[n] = fb[n*3+2];
    }
    __syncthreads();

    int lane = t & 63, wave = t >> 6;
    int wr = wave >> 1, wc = wave & 1;
    int q = lane >> 4, c16 = lane & 15;
    int r0 = rt*128, n0 = ct*128;
    f32x4 acc[4][4] = {};

    int nloc = t >> 1;
    float lxn = lxs[n0 + nloc], lyn = lys[n0 + nloc];
    int mh = (t & 1) * 32;

    for (int kk = 0; kk < Nx; kk += 64) {
        // stage A tile: 128 rows x 64 k  (1024 float4 loads across 256 thr)
        #pragma unroll
        for (int cc = 0; cc < 4; ++cc) {
            int c = t + cc*256;
            int row = c >> 3;
            int ko = (c & 7) * 8;
            *(float4*)&Als[row][ko] = *(const float4*)(A + (size_t)(r0+row)*Nx + kk + ko);
        }
        // generate adj tile (bf16) straight into LDS: 128 cols x 64 m
        #pragma unroll
        for (int g = 0; g < 4; ++g) {
            union { ushort u[8]; float4 v; } pk;
            #pragma unroll
            for (int e = 0; e < 8; ++e) {
                int m = kk + mh + g*8 + e;
                float dx = lxs[m] - lxn;
                float dy = lys[m] - lyn;
                float s = fmaf(0.5f*dx, dx, fmaf(0.5f*dy, dy, 1.0f));
                pk.u[e] = f2bf(__builtin_amdgcn_rcpf(s));
            }
            *(float4*)&Bls[nloc][mh + g*8] = pk.v;
        }
        __syncthreads();
        #pragma unroll
        for (int ks = 0; ks < 64; ks += 32) {
            bf16x8 af[4], bfr[4];
            #pragma unroll
            for (int i = 0; i < 4; ++i)
                af[i] = *(const bf16x8*)&Als[wr*64 + i*16 + c16][ks + q*8];
            #pragma unroll
            for (int j = 0; j < 4; ++j)
                bfr[j] = *(const bf16x8*)&Bls[wc*64 + j*16 + c16][ks + q*8];
            #pragma unroll
            for (int i = 0; i < 4; ++i)
                #pragma unroll
                for (int j = 0; j < 4; ++j)
                    acc[i][j] = __builtin_amdgcn_mfma_f32_16x16x32_bf16(af[i], bfr[j], acc[i][j], 0, 0, 0);
        }
        __syncthreads();
    }
    #pragma unroll
    for (int i = 0; i < 4; ++i) {
        int rowb = r0 + wr*64 + i*16 + q*4;
        #pragma unroll
        for (int j = 0; j < 4; ++j) {
            int col = n0 + wc*64 + j*16 + c16;
            #pragma unroll
            for (int r = 0; r < 4; ++r) {
                float v = fmaxf(acc[i][j][r] + bias[rowb + r], 0.0f);
                outT[(size_t)(rowb + r)*Nx + col] = f2bf(v);
            }
        }
    }
}

// ---------------------------------------------------------------------------
// kGstd: C[row][col] = sum_k Ash[row][k] * Bval[k][col]
// Ash: shared [256][K] bf16 (c1h or w2t). B per-b from sT buffer:
//   TRB=false: global [col][K] (ldb=K)
//   TRB=true : global [k][NC]  (ldb=NC) -- staged with on-the-fly transpose
// out per-b [256][NC] bf16, no activation.
// ---------------------------------------------------------------------------
template<int K, int NC, bool TRB>
__global__ __launch_bounds__(256) void kGstd(
    const ushort* __restrict__ Ash, const ushort* __restrict__ Ball,
    ushort* __restrict__ outAll)
{
    constexpr int CT = NC / 128;
    int b  = blockIdx.y;
    int rt = blockIdx.x / CT;
    int ct = blockIdx.x % CT;
    const ushort* B = Ball + (size_t)b*HIDx*Nx;
    ushort* outp = outAll + (size_t)b*HIDx*NC;

    __shared__ short Als[128][LDAP];
    __shared__ short Bls[128][LDAP];
    int t = threadIdx.x;
    int lane = t & 63, wave = t >> 6;
    int wr = wave >> 1, wc = wave & 1;
    int q = lane >> 4, c16 = lane & 15;
    int r0 = rt*128, n0 = ct*128;
    f32x4 acc[4][4] = {};

    for (int kk = 0; kk < K; kk += 64) {
        #pragma unroll
        for (int cc = 0; cc < 4; ++cc) {
            int c = t + cc*256;
            int row = c >> 3;
            int ko = (c & 7) * 8;
            *(float4*)&Als[row][ko] = *(const float4*)(Ash + (size_t)(r0+row)*K + kk + ko);
        }
        if (!TRB) {
            #pragma unroll
            for (int cc = 0; cc < 4; ++cc) {
                int c = t + cc*256;
                int row = c >> 3;
                int ko = (c & 7) * 8;
                *(float4*)&Bls[row][ko] = *(const float4*)(B + (size_t)(n0+row)*K + kk + ko);
            }
        } else {
            int pi  = t & 31;          // k-pair index
            int nc8 = t >> 5;          // 8 column-chunks of 16
            int hk = kk + 2*pi;
            const ushort* g0 = B + (size_t)hk*NC + n0 + nc8*16;
            const ushort* g1 = g0 + NC;
            float4 v0a = *(const float4*)g0;
            float4 v0b = *(const float4*)(g0 + 8);
            float4 v1a = *(const float4*)g1;
            float4 v1b = *(const float4*)(g1 + 8);
            const ushort* pa = (const ushort*)&v0a;
            const ushort* pb = (const ushort*)&v0b;
            const ushort* qa = (const ushort*)&v1a;
            const ushort* qb = (const ushort*)&v1b;
            #pragma unroll
            for (int e = 0; e < 8; ++e) {
                *(uint*)&Bls[nc8*16 + e][2*pi]     = (uint)pa[e] | ((uint)qa[e] << 16);
                *(uint*)&Bls[nc8*16 + 8 + e][2*pi] = (uint)pb[e] | ((uint)qb[e] << 16);
            }
        }
        __syncthreads();
        #pragma unroll
        for (int ks = 0; ks < 64; ks += 32) {
            bf16x8 af[4], bfr[4];
            #pragma unroll
            for (int i = 0; i < 4; ++i)
                af[i] = *(const bf16x8*)&Als[wr*64 + i*16 + c16][ks + q*8];
            #pragma unroll
            for (int j = 0; j < 4; ++j)
                bfr[j] = *(const bf16x8*)&Bls[wc*64 + j*16 + c16][ks + q*8];
            #pragma unroll
            for (int i = 0; i < 4; ++i)
                #pragma unroll
                for (int j = 0; j < 4; ++j)
                    acc[i][j] = __builtin_amdgcn_mfma_f32_16x16x32_bf16(af[i], bfr[j], acc[i][j], 0, 0, 0);
        }
        __syncthreads();
    }
    #pragma unroll
    for (int i = 0; i < 4; ++i) {
        int rowb = r0 + wr*64 + i*16 + q*4;
        #pragma unroll
        for (int j = 0; j < 4; ++j) {
            int col = n0 + wc*64 + j*16 + c16;
            #pragma unroll
            for (int r = 0; r < 4; ++r)
                outp[(size_t)(rowb + r)*NC + col] = f2bf(acc[i][j][r]);
        }
    }
}

// ---------------------------------------------------------------------------
// F1: softmax-over-b stats for t1,t2 ([b][s][h] bf16).
// ---------------------------------------------------------------------------
__global__ __launch_bounds__(256) void kF1_stats(
    const __hip_bfloat16* __restrict__ t1, const __hip_bfloat16* __restrict__ t2,
    float* __restrict__ m1, float* __restrict__ d1,
    float* __restrict__ m2, float* __restrict__ d2)
{
    int s = blockIdx.x;
    int h = threadIdx.x;
    size_t base = (size_t)s*HIDx + h;
    const size_t str = (size_t)SIGx*HIDx;
    float mx = -3.0e38f;
    for (int b = 0; b < Bx; ++b) mx = fmaxf(mx, loadT(&t1[(size_t)b*str + base]));
    float dd = 0.0f;
    for (int b = 0; b < Bx; ++b) dd += expf(loadT(&t1[(size_t)b*str + base]) - mx);
    m1[base] = mx; d1[base] = dd;
    mx = -3.0e38f;
    for (int b = 0; b < Bx; ++b) mx = fmaxf(mx, loadT(&t2[(size_t)b*str + base]));
    dd = 0.0f;
    for (int b = 0; b < Bx; ++b) dd += expf(loadT(&t2[(size_t)b*str + base]) - mx);
    m2[base] = mx; d2[base] = dd;
}

// ---------------------------------------------------------------------------
// F2: sig[b,s] = sum_h g1 + g2
// ---------------------------------------------------------------------------
__global__ __launch_bounds__(256) void kF2_sig(
    const __hip_bfloat16* __restrict__ t1, const __hip_bfloat16* __restrict__ t2,
    const float* __restrict__ m1, const float* __restrict__ d1,
    const float* __restrict__ m2, const float* __restrict__ d2,
    float* __restrict__ sig)
{
    int s = blockIdx.x;
    int b = blockIdx.y;
    int h = threadIdx.x;
    size_t sh = (size_t)s*HIDx + h;
    size_t tb = ((size_t)b*SIGx + s)*HIDx + h;
    float v = expf(loadT(&t1[tb]) - m1[sh]) / d1[sh]
            + expf(loadT(&t2[tb]) - m2[sh]) / d2[sh];
    __shared__ float red[256];
    red[h] = v;
    __syncthreads();
    for (int st = 128; st > 0; st >>= 1) {
        if (h < st) red[h] += red[h+st];
        __syncthreads();
    }
    if (h == 0) sig[(size_t)b*SIGx + s] = red[0];
}

// ---------------------------------------------------------------------------
// G: out[b,:] = softmax(sig[b,:] @ fcf_w.T + fcf_b)
// ---------------------------------------------------------------------------
__global__ __launch_bounds__(256) void kG_out(
    const float* __restrict__ sig, const float* __restrict__ fw,
    const float* __restrict__ fb, float* __restrict__ out)
{
    int b = blockIdx.x;
    int tid = threadIdx.x;
    __shared__ float red[256];
    __shared__ float logits[OUTx];
    float sv = sig[(size_t)b*SIGx + tid];
    for (int o = 0; o < OUTx; ++o) {
        red[tid] = sv * fw[o*SIGx + tid];
        __syncthreads();
        for (int st = 128; st > 0; st >>= 1) {
            if (tid < st) red[tid] += red[tid+st];
            __syncthreads();
        }
        if (tid == 0) logits[o] = red[0] + fb[o];
        __syncthreads();
    }
    if (tid == 0) {
        float mx = logits[0];
        for (int o = 1; o < OUTx; ++o) mx = fmaxf(mx, logits[o]);
        float dd = 0.0f; float e[OUTx];
        for (int o = 0; o < OUTx; ++o) { e[o] = expf(logits[o]-mx); dd += e[o]; }
        float inv = 1.0f/dd;
        for (int o = 0; o < OUTx; ++o) out[(size_t)b*OUTx + o] = e[o]*inv;
    }
}

// ---------------------------------------------------------------------------
static inline size_t alignup(size_t b) { return (b + 255) & ~(size_t)255; }

extern "C" void kernel_launch(void* const* d_in, const int* in_sizes, int n_in,
                              void* d_out, int out_size, void* d_ws, size_t ws_size,
                              hipStream_t stream)
{
    const float* x   = (const float*)d_in[0];
    // d_in[1] = unif -- dead
    const float* z   = (const float*)d_in[2];
    const float* mg  = (const float*)d_in[3];
    const float* w1  = (const float*)d_in[4];
    const float* b1  = (const float*)d_in[5];
    const float* w2  = (const float*)d_in[6];
    const float* b2  = (const float*)d_in[7];
    const float* c1  = (const float*)d_in[8];
    const float* c2  = (const float*)d_in[9];
    const float* fw  = (const float*)d_in[10];
    const float* fbv = (const float*)d_in[11];
    float* out = (float*)d_out;
    float* flp = out + (size_t)Bx*OUTx;
    (void)in_sizes; (void)n_in; (void)out_size;

    char* ws = (char*)d_ws;
    size_t off = 0;
    auto alloc = [&](size_t bytes) -> char* {
        char* p = ws + off; off += alignup(bytes); return p;
    };
    float*  feat = (float*)alloc((size_t)Bx*Nx*3*4);
    ushort* c1h  = (ushort*)alloc((size_t)SIGx*Nx*2);
    ushort* c2h  = (ushort*)alloc((size_t)SIGx*Nx*2);
    ushort* w2t  = (ushort*)alloc((size_t)HIDx*HIDx*2);
    ushort* t1   = (ushort*)alloc((size_t)Bx*SIGx*HIDx*2);
    ushort* t2   = (ushort*)alloc((size_t)Bx*SIGx*HIDx*2);
    float*  m1   = (float*)alloc((size_t)SIGx*HIDx*4);
    float*  d1   = (float*)alloc((size_t)SIGx*HIDx*4);
    float*  m2   = (float*)alloc((size_t)SIGx*HIDx*4);
    float*  d2   = (float*)alloc((size_t)SIGx*HIDx*4);
    float*  sig  = (float*)alloc((size_t)Bx*SIGx*4);
    size_t fixed = off;

    // largest batch-chunk whose two ping-pong bf16 buffers fit
    int BC = 1;
    for (int c = Bx; c >= 1; c >>= 1) {
        if (fixed + 2*alignup((size_t)c*HIDx*Nx*2) <= ws_size) { BC = c; break; }
    }
    ushort* P1 = (ushort*)alloc((size_t)BC*HIDx*Nx*2);   // h1t / h2t
    ushort* P2 = (ushort*)alloc((size_t)BC*HIDx*Nx*2);   // s1t / s2t

    hipLaunchKernelGGL(kA_sample, dim3(Bx), dim3(Nx), 0, stream, x, z, mg, feat, flp);
    hipLaunchKernelGGL(kPrep, dim3(512), dim3(256), 0, stream, c1, c2, w2, c1h, c2h, w2t);

    const int nch = Bx / BC;
    for (int c = 0; c < nch; ++c) {
        int b0 = c * BC;
        const float* featL = feat + (size_t)b0*Nx*3;
        ushort* t1L = t1 + (size_t)b0*SIGx*HIDx;
        ushort* t2L = t2 + (size_t)b0*SIGx*HIDx;
        // h1t = (feat @ gc1_w)^T
        hipLaunchKernelGGL(kB_h1t, dim3(4, BC), dim3(256), 0, stream, featL, w1, P1);
        // s1t = relu(h1t * adj + b1)
        hipLaunchKernelGGL(kGadj, dim3(8, BC), dim3(256), 0, stream, P1, featL, b1, P2);
        // t1 = c1h @ s1
        hipLaunchKernelGGL((kGstd<512,256,false>), dim3(4, BC), dim3(256), 0, stream, c1h, P2, t1L);
        // h2t = w2t-GEMM vs s1t (transposed staging)
        hipLaunchKernelGGL((kGstd<256,512,true>), dim3(8, BC), dim3(256), 0, stream, w2t, P2, P1);
        // s2t = relu(h2t * adj + b2)
        hipLaunchKernelGGL(kGadj, dim3(8, BC), dim3(256), 0, stream, P1, featL, b2, P2);
        // t2 = c2h @ s2
        hipLaunchKernelGGL((kGstd<512,256,false>), dim3(4, BC), dim3(256), 0, stream, c2h, P2, t2L);
    }

    hipLaunchKernelGGL(kF1_stats, dim3(SIGx), dim3(256), 0, stream,
                       (const __hip_bfloat16*)t1, (const __hip_bfloat16*)t2, m1, d1, m2, d2);
    hipLaunchKernelGGL(kF2_sig, dim3(SIGx, Bx), dim3(256), 0, stream,
                       (const __hip_bfloat16*)t1, (const __hip_bfloat16*)t2, m1, d1, m2, d2, sig);
    hipLaunchKernelGGL(kG_out, dim3(Bx), dim3(256), 0, stream, sig, fw, fbv, out);
}

// Round 5
// 426.195 us; speedup vs baseline: 6.5458x; 1.2538x over previous
//
#include <hip/hip_runtime.h>
#include <hip/hip_bf16.h>
#include <math.h>

#define Bx   256
#define Nx   512
#define SIGx 256
#define HIDx 256
#define OUTx 10
#define Hx   256

#define LDAP 72   // LDS k-stride (bf16 elems): 144 B rows, 16B-aligned, banks spread

typedef __attribute__((ext_vector_type(8))) short bf16x8;
typedef __attribute__((ext_vector_type(4))) float f32x4;

__device__ inline ushort f2bf(float v) {
    __hip_bfloat16 h = __float2bfloat16(v);
    return *reinterpret_cast<ushort*>(&h);
}
__device__ inline float loadT(const __hip_bfloat16* p) { return __bfloat162float(*p); }

// ---------------------------------------------------------------------------
// Kernel A: sampling stage (mixture fields constant over m => unif dead).
// ---------------------------------------------------------------------------
__global__ __launch_bounds__(512) void kA_sample(
    const float* __restrict__ x, const float* __restrict__ z,
    const float* __restrict__ mg, float* __restrict__ feat,
    float* __restrict__ flp)
{
    int b = blockIdx.x;
    int n = threadIdx.x;
    int g = n >> 5;
    float mux = mg[g*6+1];
    float muy = mg[g*6+2];
    float sxv = expf(mg[g*6+3]);
    float syv = expf(mg[g*6+4]);
    float rho = tanhf(mg[g*6+5]);
    float z1 = z[((size_t)b*Nx + n)*2 + 0];
    float z2 = z[((size_t)b*Nx + n)*2 + 1];
    float omr2 = 1.0f - rho*rho;
    float xs = mux + sxv*z1;
    float ys = muy + syv*(rho*z1 + sqrtf(omr2)*z2);
    float dx = xs - mux, dy = ys - muy;
    float quad = (dx*dx/(sxv*sxv) - 2.0f*rho*dx*dy/(sxv*syv) + dy*dy/(syv*syv)) / omr2;
    float logprob = -1.8378770664093453f - logf(sxv*syv) - 0.5f*logf(omr2) - 0.5f*quad;
    float lx = tanhf(xs), ly = tanhf(ys);
    int px = (int)truncf(0.5f*(lx+1.0f)*(float)Hx - 0.1f);
    int py = (int)truncf(0.5f*(ly+1.0f)*(float)Hx - 0.1f);
    px = px < 0 ? 0 : (px > Hx-1 ? Hx-1 : px);
    py = py < 0 ? 0 : (py > Hx-1 ? Hx-1 : py);
    float pv = x[(size_t)b*Hx*Hx + (size_t)px*Hx + py];
    size_t fo = ((size_t)b*Nx + n)*3;
    feat[fo+0] = pv; feat[fo+1] = lx; feat[fo+2] = ly;

    __shared__ float red[512];
    red[n] = logprob;
    __syncthreads();
    for (int st = 256; st > 0; st >>= 1) {
        if (n < st) red[n] += red[n+st];
        __syncthreads();
    }
    if (n == 0) flp[b] = red[0];
}

// ---------------------------------------------------------------------------
// Prep: c1,c2 -> bf16; w2 -> w2t bf16 (transposed).
// ---------------------------------------------------------------------------
__global__ __launch_bounds__(256) void kPrep(
    const float* __restrict__ c1, const float* __restrict__ c2,
    const float* __restrict__ w2,
    ushort* __restrict__ c1h, ushort* __restrict__ c2h, ushort* __restrict__ w2t)
{
    int idx = blockIdx.x*256 + threadIdx.x;
    if (idx < SIGx*Nx) {
        c1h[idx] = f2bf(c1[idx]);
        c2h[idx] = f2bf(c2[idx]);
    }
    if (idx < HIDx*HIDx) {
        int i = idx >> 8, j = idx & 255;
        w2t[idx] = f2bf(w2[j*HIDx + i]);
    }
}

// ---------------------------------------------------------------------------
// kB: h1t[b][h][n] = bf16(feat @ gc1_w)^T
// ---------------------------------------------------------------------------
__global__ __launch_bounds__(256) void kB_h1t(
    const float* __restrict__ featL, const float* __restrict__ w1,
    ushort* __restrict__ h1tAll)
{
    int b = blockIdx.y;
    int hs = blockIdx.x * 64;
    const float* fb = featL + (size_t)b*Nx*3;
    ushort* h1t = h1tAll + (size_t)b*HIDx*Nx;
    __shared__ float fpv[Nx], flx[Nx], fly[Nx];
    int t = threadIdx.x;
    for (int n = t; n < Nx; n += 256) {
        fpv[n] = fb[n*3+0]; flx[n] = fb[n*3+1]; fly[n] = fb[n*3+2];
    }
    __syncthreads();
    int n0 = 2*t;
    float p0 = fpv[n0],   x0 = flx[n0],   y0 = fly[n0];
    float p1 = fpv[n0+1], x1 = flx[n0+1], y1 = fly[n0+1];
    for (int hh = 0; hh < 64; ++hh) {
        int h = hs + hh;
        float w0 = w1[h], wA = w1[HIDx+h], wB = w1[2*HIDx+h];
        float v0 = fmaf(p0,w0, fmaf(x0,wA, y0*wB));
        float v1 = fmaf(p1,w0, fmaf(x1,wA, y1*wB));
        uint pk = (uint)f2bf(v0) | ((uint)f2bf(v1) << 16);
        *(uint*)(h1t + (size_t)h*Nx + n0) = pk;
    }
}

// ---------------------------------------------------------------------------
// kGadj: C[h][n] = sum_m A[h][m] * adj[m][n]; epilogue bias+relu -> sT.
// ---------------------------------------------------------------------------
__global__ __launch_bounds__(256) void kGadj(
    const ushort* __restrict__ Aall, const float* __restrict__ featL,
    const float* __restrict__ bias, ushort* __restrict__ outAll)
{
    int b  = blockIdx.y;
    int rt = blockIdx.x >> 2;
    int ct = blockIdx.x & 3;
    const ushort* A = Aall + (size_t)b*HIDx*Nx;
    ushort* outT = outAll + (size_t)b*HIDx*Nx;
    const float* fb = featL + (size_t)b*Nx*3;

    __shared__ short Als[128][LDAP];
    __shared__ short Bls[128][LDAP];
    __shared__ float lxs[Nx], lys[Nx];

    int t = threadIdx.x;
    for (int n = t; n < Nx; n += 256) {
        lxs[n] = fb[n*3+1];
        lys[n] = fb[n*3+2];
    }
    __syncthreads();

    int lane = t & 63, wave = t >> 6;
    int wr = wave >> 1, wc = wave & 1;
    int q = lane >> 4, c16 = lane & 15;
    int r0 = rt*128, n0 = ct*128;
    f32x4 acc[4][4] = {};

    int nloc = t >> 1;
    float lxn = lxs[n0 + nloc], lyn = lys[n0 + nloc];
    int mh = (t & 1) * 32;

    for (int kk = 0; kk < Nx; kk += 64) {
        #pragma unroll
        for (int cc = 0; cc < 4; ++cc) {
            int c = t + cc*256;
            int row = c >> 3;
            int ko = (c & 7) * 8;
            *(float4*)&Als[row][ko] = *(const float4*)(A + (size_t)(r0+row)*Nx + kk + ko);
        }
        #pragma unroll
        for (int g = 0; g < 4; ++g) {
            union { ushort u[8]; float4 v; } pk;
            #pragma unroll
            for (int e = 0; e < 8; ++e) {
                int m = kk + mh + g*8 + e;
                float dx = lxs[m] - lxn;
                float dy = lys[m] - lyn;
                float s = fmaf(0.5f*dx, dx, fmaf(0.5f*dy, dy, 1.0f));
                pk.u[e] = f2bf(__builtin_amdgcn_rcpf(s));
            }
            *(float4*)&Bls[nloc][mh + g*8] = pk.v;
        }
        __syncthreads();
        #pragma unroll
        for (int ks = 0; ks < 64; ks += 32) {
            bf16x8 af[4], bfr[4];
            #pragma unroll
            for (int i = 0; i < 4; ++i)
                af[i] = *(const bf16x8*)&Als[wr*64 + i*16 + c16][ks + q*8];
            #pragma unroll
            for (int j = 0; j < 4; ++j)
                bfr[j] = *(const bf16x8*)&Bls[wc*64 + j*16 + c16][ks + q*8];
            #pragma unroll
            for (int i = 0; i < 4; ++i)
                #pragma unroll
                for (int j = 0; j < 4; ++j)
                    acc[i][j] = __builtin_amdgcn_mfma_f32_16x16x32_bf16(af[i], bfr[j], acc[i][j], 0, 0, 0);
        }
        __syncthreads();
    }
    #pragma unroll
    for (int i = 0; i < 4; ++i) {
        int rowb = r0 + wr*64 + i*16 + q*4;
        #pragma unroll
        for (int j = 0; j < 4; ++j) {
            int col = n0 + wc*64 + j*16 + c16;
            #pragma unroll
            for (int r = 0; r < 4; ++r) {
                float v = fmaxf(acc[i][j][r] + bias[rowb + r], 0.0f);
                outT[(size_t)(rowb + r)*Nx + col] = f2bf(v);
            }
        }
    }
}

// ---------------------------------------------------------------------------
// kGstd: C[row][col] = sum_k Ash[row][k] * B[k][col]
// ---------------------------------------------------------------------------
template<int K, int NC, bool TRB>
__global__ __launch_bounds__(256) void kGstd(
    const ushort* __restrict__ Ash, const ushort* __restrict__ Ball,
    ushort* __restrict__ outAll)
{
    constexpr int CT = NC / 128;
    int b  = blockIdx.y;
    int rt = blockIdx.x / CT;
    int ct = blockIdx.x % CT;
    const ushort* B = Ball + (size_t)b*HIDx*Nx;
    ushort* outp = outAll + (size_t)b*HIDx*NC;

    __shared__ short Als[128][LDAP];
    __shared__ short Bls[128][LDAP];
    int t = threadIdx.x;
    int lane = t & 63, wave = t >> 6;
    int wr = wave >> 1, wc = wave & 1;
    int q = lane >> 4, c16 = lane & 15;
    int r0 = rt*128, n0 = ct*128;
    f32x4 acc[4][4] = {};

    for (int kk = 0; kk < K; kk += 64) {
        #pragma unroll
        for (int cc = 0; cc < 4; ++cc) {
            int c = t + cc*256;
            int row = c >> 3;
            int ko = (c & 7) * 8;
            *(float4*)&Als[row][ko] = *(const float4*)(Ash + (size_t)(r0+row)*K + kk + ko);
        }
        if (!TRB) {
            #pragma unroll
            for (int cc = 0; cc < 4; ++cc) {
                int c = t + cc*256;
                int row = c >> 3;
                int ko = (c & 7) * 8;
                *(float4*)&Bls[row][ko] = *(const float4*)(B + (size_t)(n0+row)*K + kk + ko);
            }
        } else {
            int pi  = t & 31;
            int nc8 = t >> 5;
            int hk = kk + 2*pi;
            const ushort* g0 = B + (size_t)hk*NC + n0 + nc8*16;
            const ushort* g1 = g0 + NC;
            float4 v0a = *(const float4*)g0;
            float4 v0b = *(const float4*)(g0 + 8);
            float4 v1a = *(const float4*)g1;
            float4 v1b = *(const float4*)(g1 + 8);
            const ushort* pa = (const ushort*)&v0a;
            const ushort* pb = (const ushort*)&v0b;
            const ushort* qa = (const ushort*)&v1a;
            const ushort* qb = (const ushort*)&v1b;
            #pragma unroll
            for (int e = 0; e < 8; ++e) {
                *(uint*)&Bls[nc8*16 + e][2*pi]     = (uint)pa[e] | ((uint)qa[e] << 16);
                *(uint*)&Bls[nc8*16 + 8 + e][2*pi] = (uint)pb[e] | ((uint)qb[e] << 16);
            }
        }
        __syncthreads();
        #pragma unroll
        for (int ks = 0; ks < 64; ks += 32) {
            bf16x8 af[4], bfr[4];
            #pragma unroll
            for (int i = 0; i < 4; ++i)
                af[i] = *(const bf16x8*)&Als[wr*64 + i*16 + c16][ks + q*8];
            #pragma unroll
            for (int j = 0; j < 4; ++j)
                bfr[j] = *(const bf16x8*)&Bls[wc*64 + j*16 + c16][ks + q*8];
            #pragma unroll
            for (int i = 0; i < 4; ++i)
                #pragma unroll
                for (int j = 0; j < 4; ++j)
                    acc[i][j] = __builtin_amdgcn_mfma_f32_16x16x32_bf16(af[i], bfr[j], acc[i][j], 0, 0, 0);
        }
        __syncthreads();
    }
    #pragma unroll
    for (int i = 0; i < 4; ++i) {
        int rowb = r0 + wr*64 + i*16 + q*4;
        #pragma unroll
        for (int j = 0; j < 4; ++j) {
            int col = n0 + wc*64 + j*16 + c16;
            #pragma unroll
            for (int r = 0; r < 4; ++r)
                outp[(size_t)(rowb + r)*NC + col] = f2bf(acc[i][j][r]);
        }
    }
}

// ---------------------------------------------------------------------------
// F1 (rewritten): single-pass online softmax-over-b stats for t1,t2.
// Grid SIGx, 1024 thr = 128 h-pairs x 8 b-groups of 32. Stores m and 1/d.
// ---------------------------------------------------------------------------
__global__ __launch_bounds__(1024) void kF1_stats(
    const ushort* __restrict__ t1, const ushort* __restrict__ t2,
    float* __restrict__ m1, float* __restrict__ rd1,
    float* __restrict__ m2, float* __restrict__ rd2)
{
    int s = blockIdx.x;
    int t = threadIdx.x;
    int hp = t & 127;           // h-pair index (h0 = 2*hp)
    int bq = t >> 7;            // 0..7, each covers 32 b
    int h0 = hp*2;
    const size_t str = (size_t)SIGx*HIDx;
    size_t base = (size_t)(bq*32)*str + (size_t)s*HIDx + h0;
    const ushort* p1 = t1 + base;
    const ushort* p2 = t2 + base;

    float m1a=-3.0e38f, d1a=0.0f, m1b=-3.0e38f, d1b=0.0f;
    float m2a=-3.0e38f, d2a=0.0f, m2b=-3.0e38f, d2b=0.0f;
    #pragma unroll 4
    for (int i = 0; i < 32; ++i) {
        uint u1 = *(const uint*)(p1 + (size_t)i*str);
        uint u2 = *(const uint*)(p2 + (size_t)i*str);
        float va = __uint_as_float(u1 << 16);
        float vb = __uint_as_float(u1 & 0xffff0000u);
        float wa = __uint_as_float(u2 << 16);
        float wb = __uint_as_float(u2 & 0xffff0000u);
        float mn;
        mn = fmaxf(m1a, va); d1a = d1a*__expf(m1a-mn) + __expf(va-mn); m1a = mn;
        mn = fmaxf(m1b, vb); d1b = d1b*__expf(m1b-mn) + __expf(vb-mn); m1b = mn;
        mn = fmaxf(m2a, wa); d2a = d2a*__expf(m2a-mn) + __expf(wa-mn); m2a = mn;
        mn = fmaxf(m2b, wb); d2b = d2b*__expf(m2b-mn) + __expf(wb-mn); m2b = mn;
    }

    __shared__ float pm1[8][256], pd1[8][256], pm2[8][256], pd2[8][256];
    pm1[bq][h0] = m1a; pd1[bq][h0] = d1a;
    pm1[bq][h0+1] = m1b; pd1[bq][h0+1] = d1b;
    pm2[bq][h0] = m2a; pd2[bq][h0] = d2a;
    pm2[bq][h0+1] = m2b; pd2[bq][h0+1] = d2b;
    __syncthreads();

    if (t < 256) {
        int h = t;
        float m = -3.0e38f, d = 0.0f;
        #pragma unroll
        for (int j = 0; j < 8; ++j) {
            float mm = pm1[j][h], dd = pd1[j][h];
            float mn = fmaxf(m, mm);
            d = d*__expf(m-mn) + dd*__expf(mm-mn);
            m = mn;
        }
        size_t o = (size_t)s*HIDx + h;
        m1[o] = m; rd1[o] = 1.0f/d;
    } else if (t < 512) {
        int h = t - 256;
        float m = -3.0e38f, d = 0.0f;
        #pragma unroll
        for (int j = 0; j < 8; ++j) {
            float mm = pm2[j][h], dd = pd2[j][h];
            float mn = fmaxf(m, mm);
            d = d*__expf(m-mn) + dd*__expf(mm-mn);
            m = mn;
        }
        size_t o = (size_t)s*HIDx + h;
        m2[o] = m; rd2[o] = 1.0f/d;
    }
}

// ---------------------------------------------------------------------------
// F2: sig[b,s] = sum_h exp(t1-m1)*rd1 + exp(t2-m2)*rd2
// ---------------------------------------------------------------------------
__global__ __launch_bounds__(256) void kF2_sig(
    const __hip_bfloat16* __restrict__ t1, const __hip_bfloat16* __restrict__ t2,
    const float* __restrict__ m1, const float* __restrict__ rd1,
    const float* __restrict__ m2, const float* __restrict__ rd2,
    float* __restrict__ sig)
{
    int s = blockIdx.x;
    int b = blockIdx.y;
    int h = threadIdx.x;
    size_t sh = (size_t)s*HIDx + h;
    size_t tb = ((size_t)b*SIGx + s)*HIDx + h;
    float v = __expf(loadT(&t1[tb]) - m1[sh]) * rd1[sh]
            + __expf(loadT(&t2[tb]) - m2[sh]) * rd2[sh];
    __shared__ float red[256];
    red[h] = v;
    __syncthreads();
    for (int st = 128; st > 0; st >>= 1) {
        if (h < st) red[h] += red[h+st];
        __syncthreads();
    }
    if (h == 0) sig[(size_t)b*SIGx + s] = red[0];
}

// ---------------------------------------------------------------------------
// G: out[b,:] = softmax(sig[b,:] @ fcf_w.T + fcf_b)
// ---------------------------------------------------------------------------
__global__ __launch_bounds__(256) void kG_out(
    const float* __restrict__ sig, const float* __restrict__ fw,
    const float* __restrict__ fb, float* __restrict__ out)
{
    int b = blockIdx.x;
    int tid = threadIdx.x;
    __shared__ float red[256];
    __shared__ float logits[OUTx];
    float sv = sig[(size_t)b*SIGx + tid];
    for (int o = 0; o < OUTx; ++o) {
        red[tid] = sv * fw[o*SIGx + tid];
        __syncthreads();
        for (int st = 128; st > 0; st >>= 1) {
            if (tid < st) red[tid] += red[tid+st];
            __syncthreads();
        }
        if (tid == 0) logits[o] = red[0] + fb[o];
        __syncthreads();
    }
    if (tid == 0) {
        float mx = logits[0];
        for (int o = 1; o < OUTx; ++o) mx = fmaxf(mx, logits[o]);
        float dd = 0.0f; float e[OUTx];
        for (int o = 0; o < OUTx; ++o) { e[o] = expf(logits[o]-mx); dd += e[o]; }
        float inv = 1.0f/dd;
        for (int o = 0; o < OUTx; ++o) out[(size_t)b*OUTx + o] = e[o]*inv;
    }
}

// ---------------------------------------------------------------------------
static inline size_t alignup(size_t b) { return (b + 255) & ~(size_t)255; }

extern "C" void kernel_launch(void* const* d_in, const int* in_sizes, int n_in,
                              void* d_out, int out_size, void* d_ws, size_t ws_size,
                              hipStream_t stream)
{
    const float* x   = (const float*)d_in[0];
    // d_in[1] = unif -- dead
    const float* z   = (const float*)d_in[2];
    const float* mg  = (const float*)d_in[3];
    const float* w1  = (const float*)d_in[4];
    const float* b1  = (const float*)d_in[5];
    const float* w2  = (const float*)d_in[6];
    const float* b2  = (const float*)d_in[7];
    const float* c1  = (const float*)d_in[8];
    const float* c2  = (const float*)d_in[9];
    const float* fw  = (const float*)d_in[10];
    const float* fbv = (const float*)d_in[11];
    float* out = (float*)d_out;
    float* flp = out + (size_t)Bx*OUTx;
    (void)in_sizes; (void)n_in; (void)out_size;

    char* ws = (char*)d_ws;
    size_t off = 0;
    auto alloc = [&](size_t bytes) -> char* {
        char* p = ws + off; off += alignup(bytes); return p;
    };
    float*  feat = (float*)alloc((size_t)Bx*Nx*3*4);
    ushort* c1h  = (ushort*)alloc((size_t)SIGx*Nx*2);
    ushort* c2h  = (ushort*)alloc((size_t)SIGx*Nx*2);
    ushort* w2t  = (ushort*)alloc((size_t)HIDx*HIDx*2);
    ushort* t1   = (ushort*)alloc((size_t)Bx*SIGx*HIDx*2);
    ushort* t2   = (ushort*)alloc((size_t)Bx*SIGx*HIDx*2);
    float*  m1   = (float*)alloc((size_t)SIGx*HIDx*4);
    float*  d1   = (float*)alloc((size_t)SIGx*HIDx*4);
    float*  m2   = (float*)alloc((size_t)SIGx*HIDx*4);
    float*  d2   = (float*)alloc((size_t)SIGx*HIDx*4);
    float*  sig  = (float*)alloc((size_t)Bx*SIGx*4);
    size_t fixed = off;

    int BC = 1;
    for (int c = Bx; c >= 1; c >>= 1) {
        if (fixed + 2*alignup((size_t)c*HIDx*Nx*2) <= ws_size) { BC = c; break; }
    }
    ushort* P1 = (ushort*)alloc((size_t)BC*HIDx*Nx*2);   // h1t / h2t
    ushort* P2 = (ushort*)alloc((size_t)BC*HIDx*Nx*2);   // s1t / s2t

    hipLaunchKernelGGL(kA_sample, dim3(Bx), dim3(Nx), 0, stream, x, z, mg, feat, flp);
    hipLaunchKernelGGL(kPrep, dim3(512), dim3(256), 0, stream, c1, c2, w2, c1h, c2h, w2t);

    const int nch = Bx / BC;
    for (int c = 0; c < nch; ++c) {
        int b0 = c * BC;
        const float* featL = feat + (size_t)b0*Nx*3;
        ushort* t1L = t1 + (size_t)b0*SIGx*HIDx;
        ushort* t2L = t2 + (size_t)b0*SIGx*HIDx;
        hipLaunchKernelGGL(kB_h1t, dim3(4, BC), dim3(256), 0, stream, featL, w1, P1);
        hipLaunchKernelGGL(kGadj, dim3(8, BC), dim3(256), 0, stream, P1, featL, b1, P2);
        hipLaunchKernelGGL((kGstd<512,256,false>), dim3(4, BC), dim3(256), 0, stream, c1h, P2, t1L);
        hipLaunchKernelGGL((kGstd<256,512,true>), dim3(8, BC), dim3(256), 0, stream, w2t, P2, P1);
        hipLaunchKernelGGL(kGadj, dim3(8, BC), dim3(256), 0, stream, P1, featL, b2, P2);
        hipLaunchKernelGGL((kGstd<512,256,false>), dim3(4, BC), dim3(256), 0, stream, c2h, P2, t2L);
    }

    hipLaunchKernelGGL(kF1_stats, dim3(SIGx), dim3(1024), 0, stream,
                       t1, t2, m1, d1, m2, d2);
    hipLaunchKernelGGL(kF2_sig, dim3(SIGx, Bx), dim3(256), 0, stream,
                       (const __hip_bfloat16*)t1, (const __hip_bfloat16*)t2, m1, d1, m2, d2, sig);
    hipLaunchKernelGGL(kG_out, dim3(Bx), dim3(256), 0, stream, sig, fw, fbv, out);
}